// Round 7
// baseline (280.324 us; speedup 1.0000x reference)
//
#include <hip/hip_runtime.h>
#include <hip/hip_bf16.h>
#include <cstdint>

// ---------------------------------------------------------------------------
// Hamilton_V5  R7:
//  - A3: single-barrier double-buffered LDS pipeline (stage k+1 after the
//    iter-k barrier -> the forced vmcnt(0) drain waits on loads that had a
//    full compute phase to land). LDS 51 KB; occupancy unchanged (VGPR-bound
//    at 2 blocks/CU).
//  - Chain rebalance: L0 = cvt+small transposes+zero(out); L1 = Hfwd+A1+Aw2T+
//    Hw1cvt+full Aw3 fp8 transpose; L2 = A2+hgrad; L3 = Hbwd+A3.
// ---------------------------------------------------------------------------

typedef __bf16 bf16_t;
typedef __bf16 bf16x4_t __attribute__((ext_vector_type(4)));
typedef __bf16 bf16x8_t __attribute__((ext_vector_type(8)));
typedef float f32x4_t __attribute__((ext_vector_type(4)));
typedef float f32x16_t __attribute__((ext_vector_type(16)));
typedef int intx4_t __attribute__((ext_vector_type(4)));
typedef int intx8_t __attribute__((ext_vector_type(8)));

#define DIMD 128
#define NROW 4096
#define SMEM_BYTES 18432   // launch1/launch2 (gemm 16.4K, transpose 4.2K)
#define SMEM3_BYTES 51200  // launch3: a3 dbuf 2*(16384+8192) + 512*4

// branchless tanh: t=2^(2x*log2e); tanh=1-2/(t+1).
__device__ __forceinline__ float fast_tanh(float x) {
  float t = __builtin_amdgcn_exp2f(x * 2.8853900817779268f);
  return 1.f - 2.f * __builtin_amdgcn_rcpf(t + 1.f);
}

// f32 -> fp8 e4m3 (OCP), RNE+sat via HW cvt
__device__ __forceinline__ uint8_t to_fp8(float x) {
  return (uint8_t)(__builtin_amdgcn_cvt_pk_fp8_f32(x, x, 0, false) & 0xff);
}

// async global->LDS, 16B per lane; LDS dest = wave-uniform base + lane*16
__device__ __forceinline__ void g2l16(const void* gp, void* lp) {
  __builtin_amdgcn_global_load_lds(
      reinterpret_cast<__attribute__((address_space(1))) void*>(
          reinterpret_cast<uintptr_t>(gp)),
      reinterpret_cast<__attribute__((address_space(3))) void*>(
          reinterpret_cast<uintptr_t>(lp)),
      16, 0, 0);
}

// ---------------------------------------------------------------------------
// bf16 GEMM body, C = A(MxK) * B^T(NxK)^T, 128x128x32 tile, 4 waves 2x2.
// LDS swizzle: row r's 16B k-chunk kc at slot kc ^ ((r>>1)&3) (0 conflicts).
// EPI 0: bf16 tanh(C+b); EPI 1: dx plain store / dv atomicAdd(-C);
// EPI 3: fp8 x64.
// ---------------------------------------------------------------------------
template <int EPI>
__device__ __forceinline__ void gemm_body(char* smem, int bx, int by,
                                          const bf16_t* A, int lda,
                                          const bf16_t* B, int ldb, int K,
                                          const float* bias, void* outp,
                                          int ldo) {
  constexpr int BK = 32;
  bf16_t* As = (bf16_t*)smem;  // 128*32
  bf16_t* Bs = As + 4096;

  const int m0 = bx * 128;
  const int n0 = by * 128;
  const int tid = threadIdx.x;
  const int wave = tid >> 6;
  const int lane = tid & 63;
  const int wm = wave >> 1;
  const int wn = wave & 1;

  const int sr = lane >> 2;
  const int sk = (((lane & 3) ^ ((sr >> 1) & 3)) * 8);
  const int fr = lane & 15;
  const int fk = (((lane >> 4) ^ ((fr >> 1) & 3)) * 8);

  f32x4_t acc[4][4] = {};

  for (int k0 = 0; k0 < K; k0 += BK) {
    if (k0) __syncthreads();
#pragma unroll
    for (int t = 0; t < 2; ++t) {
      const int rb = wave * 32 + t * 16;
      g2l16(A + (size_t)(m0 + rb + sr) * lda + (k0 + sk), As + rb * BK);
      g2l16(B + (size_t)(n0 + rb + sr) * ldb + (k0 + sk), Bs + rb * BK);
    }
    __syncthreads();

    bf16x8_t af[4], bb[4];
#pragma unroll
    for (int t = 0; t < 4; ++t) {
      af[t] = *(const bf16x8_t*)(As + (wm * 64 + t * 16 + fr) * BK + fk);
      bb[t] = *(const bf16x8_t*)(Bs + (wn * 64 + t * 16 + fr) * BK + fk);
    }
#pragma unroll
    for (int i = 0; i < 4; ++i)
#pragma unroll
      for (int j = 0; j < 4; ++j)
        acc[i][j] = __builtin_amdgcn_mfma_f32_16x16x32_bf16(af[i], bb[j],
                                                            acc[i][j], 0, 0, 0);
  }

  // C/D layout (m89): col = lane&15, row = (lane>>4)*4 + reg
  if constexpr (EPI == 0) {
    bf16_t* O = (bf16_t*)outp;
#pragma unroll
    for (int i = 0; i < 4; ++i) {
      const int row = m0 + wm * 64 + i * 16 + (lane >> 4) * 4;
#pragma unroll
      for (int j = 0; j < 4; ++j) {
        const int col = n0 + wn * 64 + j * 16 + fr;
        const float b = bias[col];
#pragma unroll
        for (int r = 0; r < 4; ++r)
          O[(size_t)(row + r) * ldo + col] = (bf16_t)fast_tanh(acc[i][j][r] + b);
      }
    }
  } else if constexpr (EPI == 1) {
    float* O = (float*)outp;
    const bool dx = (n0 < DIMD);
#pragma unroll
    for (int i = 0; i < 4; ++i) {
      const int row = m0 + wm * 64 + i * 16 + (lane >> 4) * 4;
#pragma unroll
      for (int j = 0; j < 4; ++j) {
        const int col = n0 + wn * 64 + j * 16 + fr;
#pragma unroll
        for (int r = 0; r < 4; ++r) {
          const size_t idx = (size_t)(row + r) * ldo + col;
          if (dx) O[idx] = acc[i][j][r];
          else atomicAdd(&O[idx], -acc[i][j][r]);  // dv_H shares with dvA
        }
      }
    }
  } else {  // EPI 3: fp8 x64 output
    uint8_t* O = (uint8_t*)outp;
#pragma unroll
    for (int i = 0; i < 4; ++i) {
      const int row = m0 + wm * 64 + i * 16 + (lane >> 4) * 4;
#pragma unroll
      for (int j = 0; j < 4; ++j) {
        const int col = n0 + wn * 64 + j * 16 + fr;
        const float b = bias[col];
#pragma unroll
        for (int r = 0; r < 4; ++r)
          O[(size_t)(row + r) * ldo + col] =
              to_fp8(64.f * fast_tanh(acc[i][j][r] + b));
      }
    }
  }
}

// ---------------------------------------------------------------------------
// A3 fused GEMM, MX-fp8, wave grid (4,1): BM=256, BN=128, BK=64, double-
// buffered LDS, ONE barrier per iter. Stage(k+1) is issued right after the
// iter-k barrier, so the compiler's vmcnt(0)-before-barrier at iter k+1 waits
// on loads that already had a full compute phase (~1 us) to land.
// out[m, 128+by] += sum_n tanh(C[m,n]+Ab3[n]) * u[n] via global atomicAdd.
// ---------------------------------------------------------------------------
__device__ __forceinline__ void a3_body(char* smem, int bx, int by,
                                        const uint8_t* A, const uint8_t* B,
                                        float* out, const float* ab3,
                                        const float* uvec) {
  constexpr int BK = 64, K = 1024, NIT = K / BK;
  uint8_t* As = (uint8_t*)smem;          // 2 x 16384
  uint8_t* Bs = (uint8_t*)smem + 32768;  // 2 x 8192
  float* red = (float*)(smem + 49152);   // 256
  float* us = red + 256;                 // 128
  float* a3s = us + 128;                 // 128

  const int m0 = bx * 256;
  const int n0 = by * 128;
  const int tid = threadIdx.x;
  const int wave = tid >> 6;
  const int lane = tid & 63;

  red[tid] = 0.f;
  if (tid < 128) {
    us[tid] = uvec[tid];
    a3s[tid] = ab3[n0 + tid];
  }

  const int sr = lane >> 2;
  const int sk = ((lane & 3) ^ ((sr >> 1) & 3)) * 16;
  const uint8_t* pA = A + (size_t)(m0 + wave * 16 + sr) * K + sk;
  const uint8_t* pB = B + (size_t)(n0 + wave * 16 + sr) * K + sk;

  const int rl = lane & 31;
  const int w = (rl >> 1) & 3;
  const int c0 = lane >> 5;
  const int sLo = ((2 * c0) ^ w) * 16;
  const int sHi = ((2 * c0 + 1) ^ w) * 16;

  f32x16_t acc[2][4] = {};

  // stage tile (global k-offset kk) into buffer buf
  auto stage = [&](int kk, int buf) {
    uint8_t* Ad = As + buf * 16384 + wave * 16 * BK;
    uint8_t* Bd = Bs + buf * 8192 + wave * 16 * BK;
#pragma unroll
    for (int t = 0; t < 4; ++t)
      g2l16(pA + (size_t)t * 64 * K + kk, Ad + t * 64 * BK);
#pragma unroll
    for (int t = 0; t < 2; ++t)
      g2l16(pB + (size_t)t * 64 * K + kk, Bd + t * 64 * BK);
  };

  stage(0, 0);
#pragma unroll 2
  for (int it = 0; it < NIT; ++it) {
    __syncthreads();  // drains DMAs issued one full compute phase ago
    if (it + 1 < NIT) stage((it + 1) * BK, (it + 1) & 1);

    const uint8_t* Ac = As + (it & 1) * 16384;
    const uint8_t* Bc = Bs + (it & 1) * 8192;
    intx8_t af[2], bfr[4];
#pragma unroll
    for (int i = 0; i < 2; ++i) {
      const int ra = (wave * 64 + i * 32 + rl) * BK;
      intx4_t lo = *(const intx4_t*)(Ac + ra + sLo);
      intx4_t hi = *(const intx4_t*)(Ac + ra + sHi);
      af[i] = __builtin_shufflevector(lo, hi, 0, 1, 2, 3, 4, 5, 6, 7);
    }
#pragma unroll
    for (int j = 0; j < 4; ++j) {
      const int rb2 = (j * 32 + rl) * BK;
      intx4_t lob = *(const intx4_t*)(Bc + rb2 + sLo);
      intx4_t hib = *(const intx4_t*)(Bc + rb2 + sHi);
      bfr[j] = __builtin_shufflevector(lob, hib, 0, 1, 2, 3, 4, 5, 6, 7);
    }
#pragma unroll
    for (int i = 0; i < 2; ++i)
#pragma unroll
      for (int j = 0; j < 4; ++j)
        acc[i][j] = __builtin_amdgcn_mfma_scale_f32_32x32x64_f8f6f4(
            af[i], bfr[j], acc[i][j], 0, 0, 0, 0x79797979, 0, 0x79797979);
  }

  // C/D (m74/m101): col = lane&31, row = (reg&3) + 8*(reg>>2) + 4*(lane>>5)
  const int q = lane >> 5;
#pragma unroll
  for (int i = 0; i < 2; ++i) {
    float sums[16];
#pragma unroll
    for (int r = 0; r < 16; ++r) sums[r] = 0.f;
#pragma unroll
    for (int j = 0; j < 4; ++j) {
      const int c = j * 32 + rl;
      const float uu = us[c];
      const float b3 = a3s[c];
#pragma unroll
      for (int r = 0; r < 16; ++r) sums[r] += fast_tanh(acc[i][j][r] + b3) * uu;
    }
#pragma unroll
    for (int d = 1; d < 32; d <<= 1)
#pragma unroll
      for (int r = 0; r < 16; ++r) sums[r] += __shfl_xor(sums[r], d, 64);
    if (rl == 0) {
      const int rowb = wave * 64 + i * 32 + 4 * q;
#pragma unroll
      for (int r = 0; r < 16; ++r)
        atomicAdd(&red[rowb + (r & 3) + 8 * (r >> 2)], sums[r]);
    }
  }
  __syncthreads();
  atomicAdd(&out[(size_t)(m0 + tid) * 256 + 128 + by], red[tid]);
}

// ---------------------------------------------------------------------------
// transposes
// ---------------------------------------------------------------------------
__device__ __forceinline__ void tcvt_body(char* smem, const float* in,
                                          bf16_t* out, int R, int C, int bx,
                                          int by) {
  float(*t)[33] = (float(*)[33])smem;  // 4224 B
  const int c0 = bx * 32;
  const int r0 = by * 32;
  const int tx = threadIdx.x & 31;
  const int ty = threadIdx.x >> 5;
#pragma unroll
  for (int k = 0; k < 4; ++k)
    t[ty + k * 8][tx] = in[(size_t)(r0 + ty + k * 8) * C + c0 + tx];
  __syncthreads();
#pragma unroll
  for (int k = 0; k < 4; ++k)
    out[(size_t)(c0 + ty + k * 8) * R + r0 + tx] = (bf16_t)t[tx][ty + k * 8];
}

// Aw3 (1024 x 16384) tile -> fp8 x64, transposed (16384 x 1024), uchar4 store
__device__ __forceinline__ void aw3t_body(char* smem, const float* Aw3,
                                          uint8_t* Aw3T8, int b) {
  float(*t)[33] = (float(*)[33])smem;
  const int c0 = (b & 511) * 32;
  const int r0 = (b >> 9) * 32;
  const int tx = threadIdx.x & 31;
  const int ty = threadIdx.x >> 5;
#pragma unroll
  for (int k = 0; k < 4; ++k)
    t[ty + k * 8][tx] = Aw3[(size_t)(r0 + ty + k * 8) * 16384 + c0 + tx];
  __syncthreads();
  const int cl = threadIdx.x >> 3;      // 0..31 output row (Aw3 col)
  const int j = (threadIdx.x & 7) * 4;  // 4-byte chunk of input rows
  uchar4 v;
  v.x = to_fp8(64.f * t[j + 0][cl]);
  v.y = to_fp8(64.f * t[j + 1][cl]);
  v.z = to_fp8(64.f * t[j + 2][cl]);
  v.w = to_fp8(64.f * t[j + 3][cl]);
  *(uchar4*)(Aw3T8 + (size_t)(c0 + cl) * 1024 + r0 + j) = v;
}

// one wave handles one row: pre2 = h.Hw2; w_j = s*Hw2_j*(1-h_j^2)
__device__ __forceinline__ void hgrad_row(int row, const bf16_t* h,
                                          const float* Hw2, const float* Hb2,
                                          bf16_t* wout) {
  const int lane = threadIdx.x & 63;
  float hv[10], wv[10];
  float pre2 = 0.f;
#pragma unroll
  for (int t = 0; t < 10; ++t) {
    const int j = lane + t * 64;
    hv[t] = (float)h[(size_t)row * 640 + j];
    wv[t] = Hw2[j];
    pre2 += hv[t] * wv[t];
  }
#pragma unroll
  for (int d = 1; d < 64; d <<= 1) pre2 += __shfl_xor(pre2, d, 64);
  const float y = fast_tanh(pre2 + Hb2[0]);
  const float s = 1.f - y * y;
#pragma unroll
  for (int t = 0; t < 10; ++t) {
    const int j = lane + t * 64;
    wout[(size_t)row * 640 + j] = (bf16_t)(s * wv[t] * (1.f - hv[t] * hv[t]));
  }
}

// ---------------------------------------------------------------------------
// L0: inp cvt (1024) + Hw1T (160) + Aw1T (64) + zero-out (1024) = 2272
// ---------------------------------------------------------------------------
__global__ __launch_bounds__(256) void launch0(
    const float* __restrict__ inp, bf16_t* __restrict__ inp_bf,
    const float* __restrict__ Hw1, bf16_t* __restrict__ Hw1T,
    const float* __restrict__ Aw1, bf16_t* __restrict__ Aw1T,
    float* __restrict__ out) {
  __shared__ __align__(16) char smem[4224];
  int b = blockIdx.x;
  if (b < 1024) {
    const int i = b * 256 + threadIdx.x;
    const float4 v = ((const float4*)inp)[i];
    bf16x4_t o = {(bf16_t)v.x, (bf16_t)v.y, (bf16_t)v.z, (bf16_t)v.w};
    ((bf16x4_t*)inp_bf)[i] = o;
  } else if (b < 1184) {
    int s = b - 1024;
    tcvt_body(smem, Hw1, Hw1T, 256, 640, s % 20, s / 20);
  } else if (b < 1248) {
    int s = b - 1184;
    tcvt_body(smem, Aw1, Aw1T, 128, 512, s % 16, s / 16);
  } else {
    const int i = (b - 1248) * 256 + threadIdx.x;
    ((float4*)out)[i] = make_float4(0.f, 0.f, 0.f, 0.f);
  }
}

// ---------------------------------------------------------------------------
// L1: Hfwd (160) + A1 (128) + Aw2T (512) + Hw1_bf cvt (160) + Aw3T (16384)
//     = 17344 blocks
// ---------------------------------------------------------------------------
__global__ __launch_bounds__(256) void launch1(
    const bf16_t* __restrict__ inp_bf, const bf16_t* __restrict__ Hw1T,
    const float* __restrict__ Hb1, bf16_t* __restrict__ h_bf,
    const bf16_t* __restrict__ Aw1T, const float* __restrict__ Ab1,
    bf16_t* __restrict__ h1_bf, const float* __restrict__ Aw2,
    bf16_t* __restrict__ Aw2T, const float* __restrict__ Hw1,
    bf16_t* __restrict__ Hw1_bf, const float* __restrict__ Aw3,
    uint8_t* __restrict__ Aw3T8) {
  __shared__ __align__(16) char smem[SMEM_BYTES];
  const int b = blockIdx.x;
  if (b < 160) {
    gemm_body<0>(smem, b % 32, b / 32, inp_bf, 256, Hw1T, 256, 256, Hb1, h_bf, 640);
  } else if (b < 288) {
    const int i = b - 160;
    gemm_body<0>(smem, i % 32, i / 32, inp_bf, 256, Aw1T, 128, 128, Ab1, h1_bf, 512);
  } else if (b < 800) {
    const int s = b - 288;
    tcvt_body(smem, Aw2, Aw2T, 512, 1024, s % 32, s / 32);
  } else if (b < 960) {
    const int i = (b - 800) * 256 + threadIdx.x;
    const float4 v = ((const float4*)Hw1)[i];
    bf16x4_t o = {(bf16_t)v.x, (bf16_t)v.y, (bf16_t)v.z, (bf16_t)v.w};
    ((bf16x4_t*)Hw1_bf)[i] = o;
  } else {
    aw3t_body(smem, Aw3, Aw3T8, b - 960);
  }
}

// ---------------------------------------------------------------------------
// L2: A2->fp8 (256) + hgrad (1024) = 1280 blocks
// ---------------------------------------------------------------------------
__global__ __launch_bounds__(256) void launch2(
    const bf16_t* __restrict__ h1_bf, const bf16_t* __restrict__ Aw2T,
    const float* __restrict__ Ab2, uint8_t* __restrict__ h2_f8,
    const bf16_t* __restrict__ h_bf, const float* __restrict__ Hw2,
    const float* __restrict__ Hb2, bf16_t* __restrict__ w_bf) {
  __shared__ __align__(16) char smem[SMEM_BYTES];
  const int b = blockIdx.x;
  if (b < 256) {
    gemm_body<3>(smem, b % 32, b / 32, h1_bf, 512, Aw2T, 512, 512, Ab2, h2_f8, 1024);
  } else {
    const int row = (b - 256) * 4 + (threadIdx.x >> 6);
    hgrad_row(row, h_bf, Hw2, Hb2, w_bf);
  }
}

// ---------------------------------------------------------------------------
// L3: Hbwd (64) + A3 fused fp8 dbuf (2048, BM=256) = 2112 blocks
// ---------------------------------------------------------------------------
__global__ __launch_bounds__(256) void launch3(
    const bf16_t* __restrict__ w_bf, const bf16_t* __restrict__ Hw1_bf,
    float* __restrict__ out, const uint8_t* __restrict__ h2_f8,
    const uint8_t* __restrict__ Aw3T8, const float* __restrict__ Ab3,
    const float* __restrict__ uvec) {
  __shared__ __align__(16) char smem[SMEM3_BYTES];
  const int b = blockIdx.x;
  if (b < 64) {
    gemm_body<1>(smem, b % 32, b / 32, w_bf, 640, Hw1_bf, 640, 640, nullptr, out, 256);
  } else {
    const int i = b - 64;
    a3_body(smem, i & 15, i >> 4, h2_f8, Aw3T8, out, Ab3, uvec);
  }
}

// ---------------------------------------------------------------------------
extern "C" void kernel_launch(void* const* d_in, const int* in_sizes, int n_in,
                              void* d_out, int out_size, void* d_ws,
                              size_t ws_size, hipStream_t stream) {
  (void)in_sizes; (void)n_in; (void)out_size; (void)ws_size;
  const float* inp = (const float*)d_in[1];
  const float* Hw1 = (const float*)d_in[2];
  const float* Hb1 = (const float*)d_in[3];
  const float* Hw2 = (const float*)d_in[4];
  const float* Hb2 = (const float*)d_in[5];
  const float* Aw1 = (const float*)d_in[6];
  const float* Ab1 = (const float*)d_in[7];
  const float* Aw2 = (const float*)d_in[8];
  const float* Ab2 = (const float*)d_in[9];
  const float* Aw3 = (const float*)d_in[10];
  const float* Ab3 = (const float*)d_in[11];
  const float* u = (const float*)d_in[12];
  float* out = (float*)d_out;

  char* ws = (char*)d_ws;
  bf16_t* inp_bf = (bf16_t*)ws;   ws += (size_t)NROW * 256 * 2;
  bf16_t* Hw1_bf = (bf16_t*)ws;   ws += (size_t)256 * 640 * 2;
  bf16_t* Hw1T = (bf16_t*)ws;     ws += (size_t)640 * 256 * 2;
  bf16_t* Aw1T = (bf16_t*)ws;     ws += (size_t)512 * 128 * 2;
  bf16_t* Aw2T = (bf16_t*)ws;     ws += (size_t)1024 * 512 * 2;
  uint8_t* Aw3T8 = (uint8_t*)ws;  ws += (size_t)16384 * 1024;
  bf16_t* h_bf = (bf16_t*)ws;     ws += (size_t)NROW * 640 * 2;
  bf16_t* w_bf = (bf16_t*)ws;     ws += (size_t)NROW * 640 * 2;
  bf16_t* h1_bf = (bf16_t*)ws;    ws += (size_t)NROW * 512 * 2;
  uint8_t* h2_f8 = (uint8_t*)ws;  ws += (size_t)NROW * 1024;

  launch0<<<2272, 256, 0, stream>>>(inp, inp_bf, Hw1, Hw1T, Aw1, Aw1T, out);
  launch1<<<17344, 256, 0, stream>>>(inp_bf, Hw1T, Hb1, h_bf, Aw1T, Ab1, h1_bf,
                                     Aw2, Aw2T, Hw1, Hw1_bf, Aw3, Aw3T8);
  launch2<<<1280, 256, 0, stream>>>(h1_bf, Aw2T, Ab2, h2_f8, h_bf, Hw2, Hb2,
                                    w_bf);
  launch3<<<2112, 256, 0, stream>>>(w_bf, Hw1_bf, out, h2_f8, Aw3T8, Ab3, u);
}

// Round 8
// 272.958 us; speedup vs baseline: 1.0270x; 1.0270x over previous
//
#include <hip/hip_runtime.h>
#include <hip/hip_bf16.h>
#include <cstdint>

// ---------------------------------------------------------------------------
// Hamilton_V5  R8:
//  - A3 reverted to R6 single-buffer (dbuf regressed: occupancy halved).
//  - GEMMs stage fp32 operands inline (f32x4 load -> cvt -> swizzled
//    ds_write_b128): inp_bf/Hw1_bf buffers and their serial prep launch gone.
//    Hbwd reads Hw1 directly (row-major NxK already, no transpose).
//  - A3 block mapping bx=i>>7: 128 consecutive blocks share one h2 tile
//    (L2/L3-resident) -> FETCH 72 -> ~25 MB predicted.
// ---------------------------------------------------------------------------

typedef __bf16 bf16_t;
typedef __bf16 bf16x4_t __attribute__((ext_vector_type(4)));
typedef __bf16 bf16x8_t __attribute__((ext_vector_type(8)));
typedef float f32x4_t __attribute__((ext_vector_type(4)));
typedef float f32x16_t __attribute__((ext_vector_type(16)));
typedef int intx4_t __attribute__((ext_vector_type(4)));
typedef int intx8_t __attribute__((ext_vector_type(8)));

#define DIMD 128
#define NROW 4096
#define SMEM_BYTES 18432   // gemm 16.4K / transpose 4.2K
#define SMEM3_BYTES 26624  // a3: 24576 + 512*4

// branchless tanh: t=2^(2x*log2e); tanh=1-2/(t+1).
__device__ __forceinline__ float fast_tanh(float x) {
  float t = __builtin_amdgcn_exp2f(x * 2.8853900817779268f);
  return 1.f - 2.f * __builtin_amdgcn_rcpf(t + 1.f);
}

// f32 -> fp8 e4m3 (OCP), RNE+sat via HW cvt
__device__ __forceinline__ uint8_t to_fp8(float x) {
  return (uint8_t)(__builtin_amdgcn_cvt_pk_fp8_f32(x, x, 0, false) & 0xff);
}

// async global->LDS, 16B per lane; LDS dest = wave-uniform base + lane*16
__device__ __forceinline__ void g2l16(const void* gp, void* lp) {
  __builtin_amdgcn_global_load_lds(
      reinterpret_cast<__attribute__((address_space(1))) void*>(
          reinterpret_cast<uintptr_t>(gp)),
      reinterpret_cast<__attribute__((address_space(3))) void*>(
          reinterpret_cast<uintptr_t>(lp)),
      16, 0, 0);
}

// ---------------------------------------------------------------------------
// inline fp32 -> bf16 staging of a 128x32 tile into swizzled LDS.
// thread t: row r=t>>1, chunks c = (t&1)*2 + {0,1}; chunk c of row r lands at
// slot c ^ ((r>>1)&3)  (same layout the fragment reads expect).
// Per-instr bank check (consecutive-8 lanes): granules all distinct mod 8.
// ---------------------------------------------------------------------------
__device__ __forceinline__ void stage_f32(const float* __restrict__ src,
                                          int lda_e, int r0, int k0,
                                          bf16_t* dst) {
  const int tid = threadIdx.x;
  const int r = tid >> 1;
  const int kc0 = (tid & 1) * 2;
  const float* p = src + (size_t)(r0 + r) * lda_e + k0;
#pragma unroll
  for (int cc = 0; cc < 2; ++cc) {
    const int c = kc0 + cc;
    const float4 v0 = *(const float4*)(p + c * 8);
    const float4 v1 = *(const float4*)(p + c * 8 + 4);
    bf16x8_t w = {(bf16_t)v0.x, (bf16_t)v0.y, (bf16_t)v0.z, (bf16_t)v0.w,
                  (bf16_t)v1.x, (bf16_t)v1.y, (bf16_t)v1.z, (bf16_t)v1.w};
    *(bf16x8_t*)(dst + r * 32 + ((c ^ ((r >> 1) & 3)) * 8)) = w;
  }
}

// ---------------------------------------------------------------------------
// bf16 GEMM body, C = A(MxK) * B^T(NxK)^T, 128x128x32 tile, 4 waves 2x2.
// AF32/BF32: operand is fp32 in global, staged with inline cvt (no DMA).
// LDS swizzle: row r's 16B k-chunk kc at slot kc ^ ((r>>1)&3) (0 conflicts).
// EPI 0: bf16 tanh(C+b); EPI 1: dx plain store / dv atomicAdd(-C);
// EPI 3: fp8 x64.
// ---------------------------------------------------------------------------
template <int EPI, bool AF32, bool BF32>
__device__ __forceinline__ void gemm_body(char* smem, int bx, int by,
                                          const void* Ap, int lda,
                                          const void* Bp, int ldb, int K,
                                          const float* bias, void* outp,
                                          int ldo) {
  constexpr int BK = 32;
  bf16_t* As = (bf16_t*)smem;  // 128*32
  bf16_t* Bs = As + 4096;

  const int m0 = bx * 128;
  const int n0 = by * 128;
  const int tid = threadIdx.x;
  const int wave = tid >> 6;
  const int lane = tid & 63;
  const int wm = wave >> 1;
  const int wn = wave & 1;

  const int sr = lane >> 2;
  const int sk = (((lane & 3) ^ ((sr >> 1) & 3)) * 8);
  const int fr = lane & 15;
  const int fk = (((lane >> 4) ^ ((fr >> 1) & 3)) * 8);

  f32x4_t acc[4][4] = {};

  for (int k0 = 0; k0 < K; k0 += BK) {
    if (k0) __syncthreads();
    if constexpr (AF32) {
      stage_f32((const float*)Ap, lda, m0, k0, As);
    } else {
      const bf16_t* A = (const bf16_t*)Ap;
#pragma unroll
      for (int t = 0; t < 2; ++t) {
        const int rb = wave * 32 + t * 16;
        g2l16(A + (size_t)(m0 + rb + sr) * lda + (k0 + sk), As + rb * BK);
      }
    }
    if constexpr (BF32) {
      stage_f32((const float*)Bp, ldb, n0, k0, Bs);
    } else {
      const bf16_t* B = (const bf16_t*)Bp;
#pragma unroll
      for (int t = 0; t < 2; ++t) {
        const int rb = wave * 32 + t * 16;
        g2l16(B + (size_t)(n0 + rb + sr) * ldb + (k0 + sk), Bs + rb * BK);
      }
    }
    __syncthreads();

    bf16x8_t af[4], bb[4];
#pragma unroll
    for (int t = 0; t < 4; ++t) {
      af[t] = *(const bf16x8_t*)(As + (wm * 64 + t * 16 + fr) * BK + fk);
      bb[t] = *(const bf16x8_t*)(Bs + (wn * 64 + t * 16 + fr) * BK + fk);
    }
#pragma unroll
    for (int i = 0; i < 4; ++i)
#pragma unroll
      for (int j = 0; j < 4; ++j)
        acc[i][j] = __builtin_amdgcn_mfma_f32_16x16x32_bf16(af[i], bb[j],
                                                            acc[i][j], 0, 0, 0);
  }

  // C/D layout (m89): col = lane&15, row = (lane>>4)*4 + reg
  if constexpr (EPI == 0) {
    bf16_t* O = (bf16_t*)outp;
#pragma unroll
    for (int i = 0; i < 4; ++i) {
      const int row = m0 + wm * 64 + i * 16 + (lane >> 4) * 4;
#pragma unroll
      for (int j = 0; j < 4; ++j) {
        const int col = n0 + wn * 64 + j * 16 + fr;
        const float b = bias[col];
#pragma unroll
        for (int r = 0; r < 4; ++r)
          O[(size_t)(row + r) * ldo + col] = (bf16_t)fast_tanh(acc[i][j][r] + b);
      }
    }
  } else if constexpr (EPI == 1) {
    float* O = (float*)outp;
    const bool dx = (n0 < DIMD);
#pragma unroll
    for (int i = 0; i < 4; ++i) {
      const int row = m0 + wm * 64 + i * 16 + (lane >> 4) * 4;
#pragma unroll
      for (int j = 0; j < 4; ++j) {
        const int col = n0 + wn * 64 + j * 16 + fr;
#pragma unroll
        for (int r = 0; r < 4; ++r) {
          const size_t idx = (size_t)(row + r) * ldo + col;
          if (dx) O[idx] = acc[i][j][r];
          else atomicAdd(&O[idx], -acc[i][j][r]);  // dv_H shares with dvA
        }
      }
    }
  } else {  // EPI 3: fp8 x64 output
    uint8_t* O = (uint8_t*)outp;
#pragma unroll
    for (int i = 0; i < 4; ++i) {
      const int row = m0 + wm * 64 + i * 16 + (lane >> 4) * 4;
#pragma unroll
      for (int j = 0; j < 4; ++j) {
        const int col = n0 + wn * 64 + j * 16 + fr;
        const float b = bias[col];
#pragma unroll
        for (int r = 0; r < 4; ++r)
          O[(size_t)(row + r) * ldo + col] =
              to_fp8(64.f * fast_tanh(acc[i][j][r] + b));
      }
    }
  }
}

// ---------------------------------------------------------------------------
// A3 fused GEMM, MX-fp8 (R6 single-buffer form): wave grid (4,1), BM=256,
// BN=128, BK=64; each wave 64x128 via 2x4 mfma 32x32x64.
// out[m, 128+by] += sum_n tanh(C[m,n]+Ab3[n]) * u[n] via global atomicAdd.
// ---------------------------------------------------------------------------
__device__ __forceinline__ void a3_body(char* smem, int bx, int by,
                                        const uint8_t* A, const uint8_t* B,
                                        float* out, const float* ab3,
                                        const float* uvec) {
  constexpr int BK = 64, K = 1024;
  uint8_t* As = (uint8_t*)smem;         // 256*64 = 16384
  uint8_t* Bs = As + 16384;             // 128*64 = 8192
  float* red = (float*)(smem + 24576);  // 256
  float* us = red + 256;                // 128
  float* a3s = us + 128;                // 128

  const int m0 = bx * 256;
  const int n0 = by * 128;
  const int tid = threadIdx.x;
  const int wave = tid >> 6;
  const int lane = tid & 63;

  red[tid] = 0.f;
  if (tid < 128) {
    us[tid] = uvec[tid];
    a3s[tid] = ab3[n0 + tid];
  }

  const int sr = lane >> 2;
  const int sk = ((lane & 3) ^ ((sr >> 1) & 3)) * 16;

  const int rl = lane & 31;
  const int w = (rl >> 1) & 3;
  const int c0 = lane >> 5;
  const int sLo = ((2 * c0) ^ w) * 16;
  const int sHi = ((2 * c0 + 1) ^ w) * 16;

  f32x16_t acc[2][4] = {};

  for (int k0 = 0; k0 < K; k0 += BK) {
    if (k0) __syncthreads();
#pragma unroll
    for (int t = 0; t < 4; ++t) {
      const int rb = t * 64 + wave * 16;
      g2l16(A + (size_t)(m0 + rb + sr) * K + (k0 + sk), As + rb * BK);
    }
#pragma unroll
    for (int t = 0; t < 2; ++t) {
      const int rb = t * 64 + wave * 16;
      g2l16(B + (size_t)(n0 + rb + sr) * K + (k0 + sk), Bs + rb * BK);
    }
    __syncthreads();

    intx8_t af[2], bfr[4];
#pragma unroll
    for (int i = 0; i < 2; ++i) {
      const int ra = (wave * 64 + i * 32 + rl) * BK;
      intx4_t lo = *(const intx4_t*)(As + ra + sLo);
      intx4_t hi = *(const intx4_t*)(As + ra + sHi);
      af[i] = __builtin_shufflevector(lo, hi, 0, 1, 2, 3, 4, 5, 6, 7);
    }
#pragma unroll
    for (int j = 0; j < 4; ++j) {
      const int rb2 = (j * 32 + rl) * BK;
      intx4_t lob = *(const intx4_t*)(Bs + rb2 + sLo);
      intx4_t hib = *(const intx4_t*)(Bs + rb2 + sHi);
      bfr[j] = __builtin_shufflevector(lob, hib, 0, 1, 2, 3, 4, 5, 6, 7);
    }
#pragma unroll
    for (int i = 0; i < 2; ++i)
#pragma unroll
      for (int j = 0; j < 4; ++j)
        acc[i][j] = __builtin_amdgcn_mfma_scale_f32_32x32x64_f8f6f4(
            af[i], bfr[j], acc[i][j], 0, 0, 0, 0x79797979, 0, 0x79797979);
  }

  // C/D (m74/m101): col = lane&31, row = (reg&3) + 8*(reg>>2) + 4*(lane>>5)
  const int q = lane >> 5;
#pragma unroll
  for (int i = 0; i < 2; ++i) {
    float sums[16];
#pragma unroll
    for (int r = 0; r < 16; ++r) sums[r] = 0.f;
#pragma unroll
    for (int j = 0; j < 4; ++j) {
      const int c = j * 32 + rl;
      const float uu = us[c];
      const float b3 = a3s[c];
#pragma unroll
      for (int r = 0; r < 16; ++r) sums[r] += fast_tanh(acc[i][j][r] + b3) * uu;
    }
#pragma unroll
    for (int d = 1; d < 32; d <<= 1)
#pragma unroll
      for (int r = 0; r < 16; ++r) sums[r] += __shfl_xor(sums[r], d, 64);
    if (rl == 0) {
      const int rowb = wave * 64 + i * 32 + 4 * q;
#pragma unroll
      for (int r = 0; r < 16; ++r)
        atomicAdd(&red[rowb + (r & 3) + 8 * (r >> 2)], sums[r]);
    }
  }
  __syncthreads();
  atomicAdd(&out[(size_t)(m0 + tid) * 256 + 128 + by], red[tid]);
}

// ---------------------------------------------------------------------------
// transposes
// ---------------------------------------------------------------------------
__device__ __forceinline__ void tcvt_body(char* smem, const float* in,
                                          bf16_t* out, int R, int C, int bx,
                                          int by) {
  float(*t)[33] = (float(*)[33])smem;  // 4224 B
  const int c0 = bx * 32;
  const int r0 = by * 32;
  const int tx = threadIdx.x & 31;
  const int ty = threadIdx.x >> 5;
#pragma unroll
  for (int k = 0; k < 4; ++k)
    t[ty + k * 8][tx] = in[(size_t)(r0 + ty + k * 8) * C + c0 + tx];
  __syncthreads();
#pragma unroll
  for (int k = 0; k < 4; ++k)
    out[(size_t)(c0 + ty + k * 8) * R + r0 + tx] = (bf16_t)t[tx][ty + k * 8];
}

// Aw3 (1024 x 16384) tile -> fp8 x64, transposed (16384 x 1024), uchar4 store
__device__ __forceinline__ void aw3t_body(char* smem, const float* Aw3,
                                          uint8_t* Aw3T8, int b) {
  float(*t)[33] = (float(*)[33])smem;
  const int c0 = (b & 511) * 32;
  const int r0 = (b >> 9) * 32;
  const int tx = threadIdx.x & 31;
  const int ty = threadIdx.x >> 5;
#pragma unroll
  for (int k = 0; k < 4; ++k)
    t[ty + k * 8][tx] = Aw3[(size_t)(r0 + ty + k * 8) * 16384 + c0 + tx];
  __syncthreads();
  const int cl = threadIdx.x >> 3;      // 0..31 output row (Aw3 col)
  const int j = (threadIdx.x & 7) * 4;  // 4-byte chunk of input rows
  uchar4 v;
  v.x = to_fp8(64.f * t[j + 0][cl]);
  v.y = to_fp8(64.f * t[j + 1][cl]);
  v.z = to_fp8(64.f * t[j + 2][cl]);
  v.w = to_fp8(64.f * t[j + 3][cl]);
  *(uchar4*)(Aw3T8 + (size_t)(c0 + cl) * 1024 + r0 + j) = v;
}

// one wave handles one row: pre2 = h.Hw2; w_j = s*Hw2_j*(1-h_j^2)
__device__ __forceinline__ void hgrad_row(int row, const bf16_t* h,
                                          const float* Hw2, const float* Hb2,
                                          bf16_t* wout) {
  const int lane = threadIdx.x & 63;
  float hv[10], wv[10];
  float pre2 = 0.f;
#pragma unroll
  for (int t = 0; t < 10; ++t) {
    const int j = lane + t * 64;
    hv[t] = (float)h[(size_t)row * 640 + j];
    wv[t] = Hw2[j];
    pre2 += hv[t] * wv[t];
  }
#pragma unroll
  for (int d = 1; d < 64; d <<= 1) pre2 += __shfl_xor(pre2, d, 64);
  const float y = fast_tanh(pre2 + Hb2[0]);
  const float s = 1.f - y * y;
#pragma unroll
  for (int t = 0; t < 10; ++t) {
    const int j = lane + t * 64;
    wout[(size_t)row * 640 + j] = (bf16_t)(s * wv[t] * (1.f - hv[t] * hv[t]));
  }
}

// ---------------------------------------------------------------------------
// L0: Hw1T (160) + Aw1T (64) + Aw2T (512) + zero-out (1024) = 1760 blocks
// ---------------------------------------------------------------------------
__global__ __launch_bounds__(256) void launch0(
    const float* __restrict__ Hw1, bf16_t* __restrict__ Hw1T,
    const float* __restrict__ Aw1, bf16_t* __restrict__ Aw1T,
    const float* __restrict__ Aw2, bf16_t* __restrict__ Aw2T,
    float* __restrict__ out) {
  __shared__ __align__(16) char smem[4224];
  int b = blockIdx.x;
  if (b < 160) {
    tcvt_body(smem, Hw1, Hw1T, 256, 640, b % 20, b / 20);
  } else if (b < 224) {
    int s = b - 160;
    tcvt_body(smem, Aw1, Aw1T, 128, 512, s % 16, s / 16);
  } else if (b < 736) {
    int s = b - 224;
    tcvt_body(smem, Aw2, Aw2T, 512, 1024, s % 32, s / 32);
  } else {
    const int i = (b - 736) * 256 + threadIdx.x;
    ((float4*)out)[i] = make_float4(0.f, 0.f, 0.f, 0.f);
  }
}

// ---------------------------------------------------------------------------
// L1: Hfwd (160, A=inp fp32 inline) + A1 (128, A=inp fp32 inline) +
//     Aw3T (16384) = 16672 blocks
// ---------------------------------------------------------------------------
__global__ __launch_bounds__(256) void launch1(
    const float* __restrict__ inp, const bf16_t* __restrict__ Hw1T,
    const float* __restrict__ Hb1, bf16_t* __restrict__ h_bf,
    const bf16_t* __restrict__ Aw1T, const float* __restrict__ Ab1,
    bf16_t* __restrict__ h1_bf, const float* __restrict__ Aw3,
    uint8_t* __restrict__ Aw3T8) {
  __shared__ __align__(16) char smem[SMEM_BYTES];
  const int b = blockIdx.x;
  if (b < 160) {
    gemm_body<0, true, false>(smem, b % 32, b / 32, inp, 256, Hw1T, 256, 256,
                              Hb1, h_bf, 640);
  } else if (b < 288) {
    const int i = b - 160;
    gemm_body<0, true, false>(smem, i % 32, i / 32, inp, 256, Aw1T, 128, 128,
                              Ab1, h1_bf, 512);
  } else {
    aw3t_body(smem, Aw3, Aw3T8, b - 288);
  }
}

// ---------------------------------------------------------------------------
// L2: A2->fp8 (256) + hgrad (1024) = 1280 blocks
// ---------------------------------------------------------------------------
__global__ __launch_bounds__(256) void launch2(
    const bf16_t* __restrict__ h1_bf, const bf16_t* __restrict__ Aw2T,
    const float* __restrict__ Ab2, uint8_t* __restrict__ h2_f8,
    const bf16_t* __restrict__ h_bf, const float* __restrict__ Hw2,
    const float* __restrict__ Hb2, bf16_t* __restrict__ w_bf) {
  __shared__ __align__(16) char smem[SMEM_BYTES];
  const int b = blockIdx.x;
  if (b < 256) {
    gemm_body<3, false, false>(smem, b % 32, b / 32, h1_bf, 512, Aw2T, 512,
                               512, Ab2, h2_f8, 1024);
  } else {
    const int row = (b - 256) * 4 + (threadIdx.x >> 6);
    hgrad_row(row, h_bf, Hw2, Hb2, w_bf);
  }
}

// ---------------------------------------------------------------------------
// L3: Hbwd (64, B=Hw1 fp32 inline, no transpose needed) + A3 (2048, h2-tile-
//     grouped mapping bx=i>>7) = 2112 blocks
// ---------------------------------------------------------------------------
__global__ __launch_bounds__(256) void launch3(
    const bf16_t* __restrict__ w_bf, const float* __restrict__ Hw1,
    float* __restrict__ out, const uint8_t* __restrict__ h2_f8,
    const uint8_t* __restrict__ Aw3T8, const float* __restrict__ Ab3,
    const float* __restrict__ uvec) {
  __shared__ __align__(16) char smem[SMEM3_BYTES];
  const int b = blockIdx.x;
  if (b < 64) {
    gemm_body<1, false, true>(smem, b % 32, b / 32, w_bf, 640, Hw1, 640, 640,
                              nullptr, out, 256);
  } else {
    const int i = b - 64;
    a3_body(smem, i >> 7, i & 127, h2_f8, Aw3T8, out, Ab3, uvec);
  }
}

// ---------------------------------------------------------------------------
extern "C" void kernel_launch(void* const* d_in, const int* in_sizes, int n_in,
                              void* d_out, int out_size, void* d_ws,
                              size_t ws_size, hipStream_t stream) {
  (void)in_sizes; (void)n_in; (void)out_size; (void)ws_size;
  const float* inp = (const float*)d_in[1];
  const float* Hw1 = (const float*)d_in[2];
  const float* Hb1 = (const float*)d_in[3];
  const float* Hw2 = (const float*)d_in[4];
  const float* Hb2 = (const float*)d_in[5];
  const float* Aw1 = (const float*)d_in[6];
  const float* Ab1 = (const float*)d_in[7];
  const float* Aw2 = (const float*)d_in[8];
  const float* Ab2 = (const float*)d_in[9];
  const float* Aw3 = (const float*)d_in[10];
  const float* Ab3 = (const float*)d_in[11];
  const float* u = (const float*)d_in[12];
  float* out = (float*)d_out;

  char* ws = (char*)d_ws;
  bf16_t* Hw1T = (bf16_t*)ws;     ws += (size_t)640 * 256 * 2;
  bf16_t* Aw1T = (bf16_t*)ws;     ws += (size_t)512 * 128 * 2;
  bf16_t* Aw2T = (bf16_t*)ws;     ws += (size_t)1024 * 512 * 2;
  uint8_t* Aw3T8 = (uint8_t*)ws;  ws += (size_t)16384 * 1024;
  bf16_t* h_bf = (bf16_t*)ws;     ws += (size_t)NROW * 640 * 2;
  bf16_t* w_bf = (bf16_t*)ws;     ws += (size_t)NROW * 640 * 2;
  bf16_t* h1_bf = (bf16_t*)ws;    ws += (size_t)NROW * 512 * 2;
  uint8_t* h2_f8 = (uint8_t*)ws;  ws += (size_t)NROW * 1024;

  launch0<<<1760, 256, 0, stream>>>(Hw1, Hw1T, Aw1, Aw1T, Aw2, Aw2T, out);
  launch1<<<16672, 256, 0, stream>>>(inp, Hw1T, Hb1, h_bf, Aw1T, Ab1, h1_bf,
                                     Aw3, Aw3T8);
  launch2<<<1280, 256, 0, stream>>>(h1_bf, Aw2T, Ab2, h2_f8, h_bf, Hw2, Hb2,
                                    w_bf);
  launch3<<<2112, 256, 0, stream>>>(w_bf, Hw1, out, h2_f8, Aw3T8, Ab3, u);
}

// Round 9
// 250.384 us; speedup vs baseline: 1.1196x; 1.0902x over previous
//
#include <hip/hip_runtime.h>
#include <hip/hip_bf16.h>
#include <cstdint>

// ---------------------------------------------------------------------------
// Hamilton_V5  R9:
//  - Small GEMMs (Hfwd/A1/A2/Hbwd) on 64x64 tiles (m92: ~343 TF regime,
//    4x block count, 6-8 blocks/CU) instead of 128x128 (~90 TF at these
//    shapes, 1 block/CU).
//  - A3 exactly R6 (single buffer, BM=256/BN=128/BK=64, mapping i&15,i>>4).
//  - Aw3T split halves across L1/L2 (R6 balance); DMA bf16 staging everywhere.
// ---------------------------------------------------------------------------

typedef __bf16 bf16_t;
typedef __bf16 bf16x4_t __attribute__((ext_vector_type(4)));
typedef __bf16 bf16x8_t __attribute__((ext_vector_type(8)));
typedef float f32x4_t __attribute__((ext_vector_type(4)));
typedef float f32x16_t __attribute__((ext_vector_type(16)));
typedef int intx4_t __attribute__((ext_vector_type(4)));
typedef int intx8_t __attribute__((ext_vector_type(8)));

#define DIMD 128
#define NROW 4096
#define SMEM_G64 8192      // gemm64 (2 x 64x32 bf16); aw3t 4224 fits
#define SMEM3_BYTES 26624  // a3: 24576 + 512*4

// branchless tanh: t=2^(2x*log2e); tanh=1-2/(t+1).
__device__ __forceinline__ float fast_tanh(float x) {
  float t = __builtin_amdgcn_exp2f(x * 2.8853900817779268f);
  return 1.f - 2.f * __builtin_amdgcn_rcpf(t + 1.f);
}

// f32 -> fp8 e4m3 (OCP), RNE+sat via HW cvt
__device__ __forceinline__ uint8_t to_fp8(float x) {
  return (uint8_t)(__builtin_amdgcn_cvt_pk_fp8_f32(x, x, 0, false) & 0xff);
}

// async global->LDS, 16B per lane; LDS dest = wave-uniform base + lane*16
__device__ __forceinline__ void g2l16(const void* gp, void* lp) {
  __builtin_amdgcn_global_load_lds(
      reinterpret_cast<__attribute__((address_space(1))) void*>(
          reinterpret_cast<uintptr_t>(gp)),
      reinterpret_cast<__attribute__((address_space(3))) void*>(
          reinterpret_cast<uintptr_t>(lp)),
      16, 0, 0);
}

// ---------------------------------------------------------------------------
// bf16 GEMM, 64x64 tile, BK=32, 4 waves 2x2 (each 32x32 = 2x2 mfma 16x16x32).
// LDS swizzle: row r's 16B k-chunk kc at slot kc ^ ((r>>1)&3) (0 conflicts,
// same pattern as the 128-tile version measured in R2).
// EPI 0: bf16 tanh(C+b); EPI 1: dx store / dv atomicAdd(-C); EPI 3: fp8 x64.
// ---------------------------------------------------------------------------
template <int EPI>
__device__ __forceinline__ void gemm64_body(char* smem, int bx, int by,
                                            const bf16_t* A, int lda,
                                            const bf16_t* B, int ldb, int K,
                                            const float* bias, void* outp,
                                            int ldo) {
  constexpr int BK = 32;
  bf16_t* As = (bf16_t*)smem;  // 64*32
  bf16_t* Bs = As + 2048;

  const int m0 = bx * 64;
  const int n0 = by * 64;
  const int tid = threadIdx.x;
  const int wave = tid >> 6;
  const int lane = tid & 63;
  const int wm = wave >> 1;
  const int wn = wave & 1;

  const int sr = lane >> 2;
  const int sk = (((lane & 3) ^ ((sr >> 1) & 3)) * 8);
  const int fr = lane & 15;
  const int fk = (((lane >> 4) ^ ((fr >> 1) & 3)) * 8);

  f32x4_t acc[2][2] = {};

  for (int k0 = 0; k0 < K; k0 += BK) {
    if (k0) __syncthreads();
    const int rb = wave * 16;  // each wave stages 16 rows of A and B
    g2l16(A + (size_t)(m0 + rb + sr) * lda + (k0 + sk), As + rb * BK);
    g2l16(B + (size_t)(n0 + rb + sr) * ldb + (k0 + sk), Bs + rb * BK);
    __syncthreads();

    bf16x8_t af[2], bb[2];
#pragma unroll
    for (int t = 0; t < 2; ++t) {
      af[t] = *(const bf16x8_t*)(As + (wm * 32 + t * 16 + fr) * BK + fk);
      bb[t] = *(const bf16x8_t*)(Bs + (wn * 32 + t * 16 + fr) * BK + fk);
    }
#pragma unroll
    for (int i = 0; i < 2; ++i)
#pragma unroll
      for (int j = 0; j < 2; ++j)
        acc[i][j] = __builtin_amdgcn_mfma_f32_16x16x32_bf16(af[i], bb[j],
                                                            acc[i][j], 0, 0, 0);
  }

  // C/D layout (m89): col = lane&15, row = (lane>>4)*4 + reg
#pragma unroll
  for (int i = 0; i < 2; ++i) {
    const int row = m0 + wm * 32 + i * 16 + (lane >> 4) * 4;
#pragma unroll
    for (int j = 0; j < 2; ++j) {
      const int col = n0 + wn * 32 + j * 16 + fr;
      if constexpr (EPI == 0) {
        bf16_t* O = (bf16_t*)outp;
        const float b = bias[col];
#pragma unroll
        for (int r = 0; r < 4; ++r)
          O[(size_t)(row + r) * ldo + col] = (bf16_t)fast_tanh(acc[i][j][r] + b);
      } else if constexpr (EPI == 1) {
        float* O = (float*)outp;
        const bool dx = (n0 < DIMD);
#pragma unroll
        for (int r = 0; r < 4; ++r) {
          const size_t idx = (size_t)(row + r) * ldo + col;
          if (dx) O[idx] = acc[i][j][r];
          else atomicAdd(&O[idx], -acc[i][j][r]);  // dv_H shares with dvA
        }
      } else {  // EPI 3
        uint8_t* O = (uint8_t*)outp;
        const float b = bias[col];
#pragma unroll
        for (int r = 0; r < 4; ++r)
          O[(size_t)(row + r) * ldo + col] =
              to_fp8(64.f * fast_tanh(acc[i][j][r] + b));
      }
    }
  }
}

// ---------------------------------------------------------------------------
// A3 fused GEMM, MX-fp8 (R6 config): wave grid (4,1), BM=256, BN=128, BK=64;
// each wave 64x128 via 2x4 mfma 32x32x64; single LDS buffer.
// out[m, 128+by] += sum_n tanh(C[m,n]+Ab3[n]) * u[n] via global atomicAdd.
// ---------------------------------------------------------------------------
__device__ __forceinline__ void a3_body(char* smem, int bx, int by,
                                        const uint8_t* A, const uint8_t* B,
                                        float* out, const float* ab3,
                                        const float* uvec) {
  constexpr int BK = 64, K = 1024;
  uint8_t* As = (uint8_t*)smem;         // 256*64 = 16384
  uint8_t* Bs = As + 16384;             // 128*64 = 8192
  float* red = (float*)(smem + 24576);  // 256
  float* us = red + 256;                // 128
  float* a3s = us + 128;                // 128

  const int m0 = bx * 256;
  const int n0 = by * 128;
  const int tid = threadIdx.x;
  const int wave = tid >> 6;
  const int lane = tid & 63;

  red[tid] = 0.f;
  if (tid < 128) {
    us[tid] = uvec[tid];
    a3s[tid] = ab3[n0 + tid];
  }

  const int sr = lane >> 2;
  const int sk = ((lane & 3) ^ ((sr >> 1) & 3)) * 16;

  const int rl = lane & 31;
  const int w = (rl >> 1) & 3;
  const int c0 = lane >> 5;
  const int sLo = ((2 * c0) ^ w) * 16;
  const int sHi = ((2 * c0 + 1) ^ w) * 16;

  f32x16_t acc[2][4] = {};

  for (int k0 = 0; k0 < K; k0 += BK) {
    if (k0) __syncthreads();
#pragma unroll
    for (int t = 0; t < 4; ++t) {
      const int rb = t * 64 + wave * 16;
      g2l16(A + (size_t)(m0 + rb + sr) * K + (k0 + sk), As + rb * BK);
    }
#pragma unroll
    for (int t = 0; t < 2; ++t) {
      const int rb = t * 64 + wave * 16;
      g2l16(B + (size_t)(n0 + rb + sr) * K + (k0 + sk), Bs + rb * BK);
    }
    __syncthreads();

    intx8_t af[2], bfr[4];
#pragma unroll
    for (int i = 0; i < 2; ++i) {
      const int ra = (wave * 64 + i * 32 + rl) * BK;
      intx4_t lo = *(const intx4_t*)(As + ra + sLo);
      intx4_t hi = *(const intx4_t*)(As + ra + sHi);
      af[i] = __builtin_shufflevector(lo, hi, 0, 1, 2, 3, 4, 5, 6, 7);
    }
#pragma unroll
    for (int j = 0; j < 4; ++j) {
      const int rb2 = (j * 32 + rl) * BK;
      intx4_t lob = *(const intx4_t*)(Bs + rb2 + sLo);
      intx4_t hib = *(const intx4_t*)(Bs + rb2 + sHi);
      bfr[j] = __builtin_shufflevector(lob, hib, 0, 1, 2, 3, 4, 5, 6, 7);
    }
#pragma unroll
    for (int i = 0; i < 2; ++i)
#pragma unroll
      for (int j = 0; j < 4; ++j)
        acc[i][j] = __builtin_amdgcn_mfma_scale_f32_32x32x64_f8f6f4(
            af[i], bfr[j], acc[i][j], 0, 0, 0, 0x79797979, 0, 0x79797979);
  }

  // C/D (m74/m101): col = lane&31, row = (reg&3) + 8*(reg>>2) + 4*(lane>>5)
  const int q = lane >> 5;
#pragma unroll
  for (int i = 0; i < 2; ++i) {
    float sums[16];
#pragma unroll
    for (int r = 0; r < 16; ++r) sums[r] = 0.f;
#pragma unroll
    for (int j = 0; j < 4; ++j) {
      const int c = j * 32 + rl;
      const float uu = us[c];
      const float b3 = a3s[c];
#pragma unroll
      for (int r = 0; r < 16; ++r) sums[r] += fast_tanh(acc[i][j][r] + b3) * uu;
    }
#pragma unroll
    for (int d = 1; d < 32; d <<= 1)
#pragma unroll
      for (int r = 0; r < 16; ++r) sums[r] += __shfl_xor(sums[r], d, 64);
    if (rl == 0) {
      const int rowb = wave * 64 + i * 32 + 4 * q;
#pragma unroll
      for (int r = 0; r < 16; ++r)
        atomicAdd(&red[rowb + (r & 3) + 8 * (r >> 2)], sums[r]);
    }
  }
  __syncthreads();
  atomicAdd(&out[(size_t)(m0 + tid) * 256 + 128 + by], red[tid]);
}

// ---------------------------------------------------------------------------
// transposes / cvt helpers
// ---------------------------------------------------------------------------
__device__ __forceinline__ void tcvt_body(char* smem, const float* in,
                                          bf16_t* out, int R, int C, int bx,
                                          int by) {
  float(*t)[33] = (float(*)[33])smem;  // 4224 B
  const int c0 = bx * 32;
  const int r0 = by * 32;
  const int tx = threadIdx.x & 31;
  const int ty = threadIdx.x >> 5;
#pragma unroll
  for (int k = 0; k < 4; ++k)
    t[ty + k * 8][tx] = in[(size_t)(r0 + ty + k * 8) * C + c0 + tx];
  __syncthreads();
#pragma unroll
  for (int k = 0; k < 4; ++k)
    out[(size_t)(c0 + ty + k * 8) * R + r0 + tx] = (bf16_t)t[tx][ty + k * 8];
}

// Aw3 (1024 x 16384) tile -> fp8 x64, transposed (16384 x 1024), uchar4 store
__device__ __forceinline__ void aw3t_body(char* smem, const float* Aw3,
                                          uint8_t* Aw3T8, int b) {
  float(*t)[33] = (float(*)[33])smem;
  const int c0 = (b & 511) * 32;
  const int r0 = (b >> 9) * 32;
  const int tx = threadIdx.x & 31;
  const int ty = threadIdx.x >> 5;
#pragma unroll
  for (int k = 0; k < 4; ++k)
    t[ty + k * 8][tx] = Aw3[(size_t)(r0 + ty + k * 8) * 16384 + c0 + tx];
  __syncthreads();
  const int cl = threadIdx.x >> 3;      // 0..31 output row (Aw3 col)
  const int j = (threadIdx.x & 7) * 4;  // 4-byte chunk of input rows
  uchar4 v;
  v.x = to_fp8(64.f * t[j + 0][cl]);
  v.y = to_fp8(64.f * t[j + 1][cl]);
  v.z = to_fp8(64.f * t[j + 2][cl]);
  v.w = to_fp8(64.f * t[j + 3][cl]);
  *(uchar4*)(Aw3T8 + (size_t)(c0 + cl) * 1024 + r0 + j) = v;
}

// one wave handles one row: pre2 = h.Hw2; w_j = s*Hw2_j*(1-h_j^2)
__device__ __forceinline__ void hgrad_row(int row, const bf16_t* h,
                                          const float* Hw2, const float* Hb2,
                                          bf16_t* wout) {
  const int lane = threadIdx.x & 63;
  float hv[10], wv[10];
  float pre2 = 0.f;
#pragma unroll
  for (int t = 0; t < 10; ++t) {
    const int j = lane + t * 64;
    hv[t] = (float)h[(size_t)row * 640 + j];
    wv[t] = Hw2[j];
    pre2 += hv[t] * wv[t];
  }
#pragma unroll
  for (int d = 1; d < 64; d <<= 1) pre2 += __shfl_xor(pre2, d, 64);
  const float y = fast_tanh(pre2 + Hb2[0]);
  const float s = 1.f - y * y;
#pragma unroll
  for (int t = 0; t < 10; ++t) {
    const int j = lane + t * 64;
    wout[(size_t)row * 640 + j] = (bf16_t)(s * wv[t] * (1.f - hv[t] * hv[t]));
  }
}

// ---------------------------------------------------------------------------
// L0: inp cvt (1024) + Hw1T (160) + Aw1T (64) + Aw2T (512) + Hw1_bf cvt (160)
//     + zero-out (1024) = 2944 blocks
// ---------------------------------------------------------------------------
__global__ __launch_bounds__(256) void launch0(
    const float* __restrict__ inp, bf16_t* __restrict__ inp_bf,
    const float* __restrict__ Hw1, bf16_t* __restrict__ Hw1T,
    bf16_t* __restrict__ Hw1_bf, const float* __restrict__ Aw1,
    bf16_t* __restrict__ Aw1T, const float* __restrict__ Aw2,
    bf16_t* __restrict__ Aw2T, float* __restrict__ out) {
  __shared__ __align__(16) char smem[4224];
  int b = blockIdx.x;
  if (b < 1024) {
    const int i = b * 256 + threadIdx.x;
    const float4 v = ((const float4*)inp)[i];
    bf16x4_t o = {(bf16_t)v.x, (bf16_t)v.y, (bf16_t)v.z, (bf16_t)v.w};
    ((bf16x4_t*)inp_bf)[i] = o;
  } else if (b < 1184) {
    int s = b - 1024;
    tcvt_body(smem, Hw1, Hw1T, 256, 640, s % 20, s / 20);
  } else if (b < 1248) {
    int s = b - 1184;
    tcvt_body(smem, Aw1, Aw1T, 128, 512, s % 16, s / 16);
  } else if (b < 1760) {
    int s = b - 1248;
    tcvt_body(smem, Aw2, Aw2T, 512, 1024, s % 32, s / 32);
  } else if (b < 1920) {
    const int i = (b - 1760) * 256 + threadIdx.x;
    const float4 v = ((const float4*)Hw1)[i];
    bf16x4_t o = {(bf16_t)v.x, (bf16_t)v.y, (bf16_t)v.z, (bf16_t)v.w};
    ((bf16x4_t*)Hw1_bf)[i] = o;
  } else {
    const int i = (b - 1920) * 256 + threadIdx.x;
    ((float4*)out)[i] = make_float4(0.f, 0.f, 0.f, 0.f);
  }
}

// ---------------------------------------------------------------------------
// L1: Hfwd 64^2 (640) + A1 64^2 (512) + Aw3T[0:8192] = 9344 blocks
// ---------------------------------------------------------------------------
__global__ __launch_bounds__(256) void launch1(
    const bf16_t* __restrict__ inp_bf, const bf16_t* __restrict__ Hw1T,
    const float* __restrict__ Hb1, bf16_t* __restrict__ h_bf,
    const bf16_t* __restrict__ Aw1T, const float* __restrict__ Ab1,
    bf16_t* __restrict__ h1_bf, const float* __restrict__ Aw3,
    uint8_t* __restrict__ Aw3T8) {
  __shared__ __align__(16) char smem[SMEM_G64];
  const int b = blockIdx.x;
  if (b < 640) {
    gemm64_body<0>(smem, b % 64, b / 64, inp_bf, 256, Hw1T, 256, 256, Hb1,
                   h_bf, 640);
  } else if (b < 1152) {
    const int i = b - 640;
    gemm64_body<0>(smem, i % 64, i / 64, inp_bf, 256, Aw1T, 128, 128, Ab1,
                   h1_bf, 512);
  } else {
    aw3t_body(smem, Aw3, Aw3T8, b - 1152);
  }
}

// ---------------------------------------------------------------------------
// L2: A2->fp8 64^2 (1024) + hgrad (1024) + Aw3T[8192:16384] = 10240 blocks
// ---------------------------------------------------------------------------
__global__ __launch_bounds__(256) void launch2(
    const bf16_t* __restrict__ h1_bf, const bf16_t* __restrict__ Aw2T,
    const float* __restrict__ Ab2, uint8_t* __restrict__ h2_f8,
    const bf16_t* __restrict__ h_bf, const float* __restrict__ Hw2,
    const float* __restrict__ Hb2, bf16_t* __restrict__ w_bf,
    const float* __restrict__ Aw3, uint8_t* __restrict__ Aw3T8) {
  __shared__ __align__(16) char smem[SMEM_G64];
  const int b = blockIdx.x;
  if (b < 1024) {
    gemm64_body<3>(smem, b % 64, b / 64, h1_bf, 512, Aw2T, 512, 512, Ab2,
                   h2_f8, 1024);
  } else if (b < 2048) {
    const int row = (b - 1024) * 4 + (threadIdx.x >> 6);
    hgrad_row(row, h_bf, Hw2, Hb2, w_bf);
  } else {
    aw3t_body(smem, Aw3, Aw3T8, 8192 + (b - 2048));
  }
}

// ---------------------------------------------------------------------------
// L3: Hbwd 64^2 (256) + A3 (2048, R6 mapping) = 2304 blocks
// ---------------------------------------------------------------------------
__global__ __launch_bounds__(256) void launch3(
    const bf16_t* __restrict__ w_bf, const bf16_t* __restrict__ Hw1_bf,
    float* __restrict__ out, const uint8_t* __restrict__ h2_f8,
    const uint8_t* __restrict__ Aw3T8, const float* __restrict__ Ab3,
    const float* __restrict__ uvec) {
  __shared__ __align__(16) char smem[SMEM3_BYTES];
  const int b = blockIdx.x;
  if (b < 256) {
    gemm64_body<1>(smem, b % 64, b / 64, w_bf, 640, Hw1_bf, 640, 640, nullptr,
                   out, 256);
  } else {
    const int i = b - 256;
    a3_body(smem, i & 15, i >> 4, h2_f8, Aw3T8, out, Ab3, uvec);
  }
}

// ---------------------------------------------------------------------------
extern "C" void kernel_launch(void* const* d_in, const int* in_sizes, int n_in,
                              void* d_out, int out_size, void* d_ws,
                              size_t ws_size, hipStream_t stream) {
  (void)in_sizes; (void)n_in; (void)out_size; (void)ws_size;
  const float* inp = (const float*)d_in[1];
  const float* Hw1 = (const float*)d_in[2];
  const float* Hb1 = (const float*)d_in[3];
  const float* Hw2 = (const float*)d_in[4];
  const float* Hb2 = (const float*)d_in[5];
  const float* Aw1 = (const float*)d_in[6];
  const float* Ab1 = (const float*)d_in[7];
  const float* Aw2 = (const float*)d_in[8];
  const float* Ab2 = (const float*)d_in[9];
  const float* Aw3 = (const float*)d_in[10];
  const float* Ab3 = (const float*)d_in[11];
  const float* u = (const float*)d_in[12];
  float* out = (float*)d_out;

  char* ws = (char*)d_ws;
  bf16_t* inp_bf = (bf16_t*)ws;   ws += (size_t)NROW * 256 * 2;
  bf16_t* Hw1_bf = (bf16_t*)ws;   ws += (size_t)256 * 640 * 2;
  bf16_t* Hw1T = (bf16_t*)ws;     ws += (size_t)640 * 256 * 2;
  bf16_t* Aw1T = (bf16_t*)ws;     ws += (size_t)512 * 128 * 2;
  bf16_t* Aw2T = (bf16_t*)ws;     ws += (size_t)1024 * 512 * 2;
  uint8_t* Aw3T8 = (uint8_t*)ws;  ws += (size_t)16384 * 1024;
  bf16_t* h_bf = (bf16_t*)ws;     ws += (size_t)NROW * 640 * 2;
  bf16_t* w_bf = (bf16_t*)ws;     ws += (size_t)NROW * 640 * 2;
  bf16_t* h1_bf = (bf16_t*)ws;    ws += (size_t)NROW * 512 * 2;
  uint8_t* h2_f8 = (uint8_t*)ws;  ws += (size_t)NROW * 1024;

  launch0<<<2944, 256, 0, stream>>>(inp, inp_bf, Hw1, Hw1T, Hw1_bf, Aw1, Aw1T,
                                    Aw2, Aw2T, out);
  launch1<<<9344, 256, 0, stream>>>(inp_bf, Hw1T, Hb1, h_bf, Aw1T, Ab1, h1_bf,
                                    Aw3, Aw3T8);
  launch2<<<10240, 256, 0, stream>>>(h1_bf, Aw2T, Ab2, h2_f8, h_bf, Hw2, Hb2,
                                     w_bf, Aw3, Aw3T8);
  launch3<<<2304, 256, 0, stream>>>(w_bf, Hw1_bf, out, h2_f8, Aw3T8, Ab3, u);
}